// Round 14
// baseline (372.610 us; speedup 1.0000x reference)
//
#include <hip/hip_runtime.h>
#include <hip/hip_bf16.h>
#include <cstddef>

#define NH 4
#define CHID 64
#define HC 256  // NH*CHID

typedef __attribute__((ext_vector_type(8))) short bf16x8;
typedef __attribute__((ext_vector_type(4))) float f32x4;

// ----------------- counting sort by dst (CSR build) -----------------

__global__ void hist_kernel(const int* __restrict__ ei, int E, int N,
                            int* __restrict__ deg) {
  int i = blockIdx.x * blockDim.x + threadIdx.x;
  int EP = E + N;
  if (i >= EP) return;
  int d = (i < E) ? ei[E + i] : (i - E);  // self-loop tail: node i-E
  atomicAdd(&deg[d], 1);
}

__global__ __launch_bounds__(256) void partial_sum_kernel(const int* __restrict__ deg,
                                                          int* __restrict__ part, int n) {
  __shared__ int red[4];
  int t = threadIdx.x;
  int i = blockIdx.x * 256 + t;
  int v = (i < n) ? deg[i] : 0;
#pragma unroll
  for (int o = 32; o; o >>= 1) v += __shfl_xor(v, o, 64);
  if ((t & 63) == 0) red[t >> 6] = v;
  __syncthreads();
  if (t == 0) part[blockIdx.x] = red[0] + red[1] + red[2] + red[3];
}

__global__ __launch_bounds__(256) void scan_part_kernel(int* __restrict__ part, int nb,
                                                        int* __restrict__ row_off, int n) {
  __shared__ int s[256];
  int t = threadIdx.x;
  int v = (t < nb) ? part[t] : 0;
  s[t] = v;
  __syncthreads();
  for (int o = 1; o < 256; o <<= 1) {
    int u = (t >= o) ? s[t - o] : 0;
    __syncthreads();
    s[t] += u;
    __syncthreads();
  }
  if (t < nb) part[t] = s[t] - v;        // exclusive base per chunk
  if (t == 255) row_off[n] = s[255];     // grand total
}

__global__ __launch_bounds__(256) void row_off_kernel(const int* __restrict__ deg,
                                                      const int* __restrict__ part,
                                                      int* __restrict__ row_off, int n) {
  __shared__ int s[256];
  int t = threadIdx.x;
  int i = blockIdx.x * 256 + t;
  int v = (i < n) ? deg[i] : 0;
  s[t] = v;
  __syncthreads();
  for (int o = 1; o < 256; o <<= 1) {
    int u = (t >= o) ? s[t - o] : 0;
    __syncthreads();
    s[t] += u;
    __syncthreads();
  }
  if (i < n) row_off[i] = part[blockIdx.x] + s[t] - v;
}

__global__ void scatter_kernel(const int* __restrict__ ei, int E, int N,
                               const int* __restrict__ row_off,
                               int* __restrict__ cursor, int* __restrict__ ssrc) {
  int i = blockIdx.x * blockDim.x + threadIdx.x;
  int EP = E + N;
  if (i >= EP) {
    if (i < EP + 8) ssrc[i] = 0;  // sentinel pad
    return;
  }
  int s, d;
  if (i < E) { s = ei[i]; d = ei[E + i]; } else { s = i - E; d = s; }
  int pos = row_off[d] + atomicAdd(&cursor[d], 1);
  ssrc[pos] = s;
}

// ----------------- prep: x -> bf16, W1/2/3 -> transposed bf16 -----------------

__global__ void prep_kernel(const float* __restrict__ x,
                            __hip_bfloat16* __restrict__ xb, int n4,
                            const float* __restrict__ W1, const float* __restrict__ W2,
                            const float* __restrict__ W3,
                            __hip_bfloat16* __restrict__ w1b,
                            __hip_bfloat16* __restrict__ w2b,
                            __hip_bfloat16* __restrict__ w3b) {
  int i = blockIdx.x * blockDim.x + threadIdx.x;
  if (i < n4) {
    float4 v = reinterpret_cast<const float4*>(x)[i];
    __hip_bfloat16 h[4] = {__float2bfloat16(v.x), __float2bfloat16(v.y),
                           __float2bfloat16(v.z), __float2bfloat16(v.w)};
    reinterpret_cast<uint2*>(xb)[i] = *reinterpret_cast<uint2*>(h);
    return;
  }
  int j = i - n4;
  if (j >= 65536) return;
  const float* W; __hip_bfloat16* wb; int K, base;
  if (j < 32768)      { W = W1; wb = w1b; K = 128; base = j; }
  else if (j < 49152) { W = W2; wb = w2b; K = 64;  base = j - 32768; }
  else                { W = W3; wb = w3b; K = 64;  base = j - 49152; }
  int k = base >> 8;
  int c = base & 255;
  wb[c * K + k] = __float2bfloat16(W[base]);
}

// ----------------- MFMA bf16 GEMM, col-split, W in LDS -----------------
// blockIdx.y = col-half ch: output cols [ch*128, ch*128+128) = heads {2ch, 2ch+1}.
// Each block handles TWO row-groups (g0 = bid, g1 = bid + gridDim.x) with BOTH
// groups' x fragments preloaded before any MFMA — group-1 loads are in flight
// during group-0's compute, hiding HBM/L3 latency. W staged once, swizzled.

template <int K>
__global__ __launch_bounds__(256) void gemm_mfma_kernel(
    const __hip_bfloat16* __restrict__ Ab,
    const __hip_bfloat16* __restrict__ Btb,
    const float* __restrict__ a_s, const float* __restrict__ a_d,
    __hip_bfloat16* __restrict__ h, float* __restrict__ asrc_n,
    float* __restrict__ adst_n, int n_rows, int row_groups) {
  extern __shared__ char smem[];
  uint4* lds4 = reinterpret_cast<uint4*>(smem);
  constexpr int KS = K / 32;                 // k0 steps
  constexpr int S16 = (128 * K * 2) >> 4;    // 16B chunks (128 W rows)
  constexpr int rowshift = (K == 128) ? 4 : 3;
  int ch = blockIdx.y;                       // col half (0/1)
  int colbase = ch * 128;

  {
    const uint4* g = reinterpret_cast<const uint4*>(Btb + (size_t)colbase * K);
    for (int c = threadIdx.x; c < S16; c += 256) {
      int row = c >> rowshift;
      lds4[c ^ (row & 7)] = g[c];
    }
  }

  int wave = threadIdx.x >> 6;
  int lane = threadIdx.x & 63;
  int n16  = lane & 15;
  int g4   = lane >> 4;
  const bf16x8 z8 = {0, 0, 0, 0, 0, 0, 0, 0};

  int gs[2] = {(int)blockIdx.x, (int)(blockIdx.x + gridDim.x)};

  // preload BOTH groups' x fragments (issued before the staging barrier wait)
  bf16x8 xh[2][KS];
  bool avals[2];
  int rows[2];
#pragma unroll
  for (int p = 0; p < 2; ++p) {
    int row0 = gs[p] * 64 + wave * 16;
    int xrow = row0 + n16;
    bool aval = (gs[p] < row_groups) && (xrow < n_rows);
    avals[p] = aval;
    rows[p] = xrow;
    size_t xbase = (size_t)xrow * K + g4 * 8;
#pragma unroll
    for (int s = 0; s < KS; ++s)
      xh[p][s] = aval ? *reinterpret_cast<const bf16x8*>(&Ab[xbase + s * 32]) : z8;
  }

  __syncthreads();

#pragma unroll
  for (int p = 0; p < 2; ++p) {
    if (gs[p] >= row_groups) break;
    f32x4 acc[8];
#pragma unroll
    for (int ct = 0; ct < 8; ++ct) acc[ct] = (f32x4){0.f, 0.f, 0.f, 0.f};

#pragma unroll
    for (int ct = 0; ct < 8; ++ct) {
      int wrow = ct * 16 + n16;  // local W row (0..127)
#pragma unroll
      for (int s = 0; s < KS; ++s) {
        int ci = ((wrow * K + s * 32 + g4 * 8) >> 3) ^ (wrow & 7);
        bf16x8 wh = *reinterpret_cast<const bf16x8*>(&lds4[ci]);
        acc[ct] = __builtin_amdgcn_mfma_f32_16x16x32_bf16(wh, xh[p][s], acc[ct], 0, 0, 0);
      }
    }

    int r = rows[p];
    bool valid = avals[p];

    if (valid) {
#pragma unroll
      for (int ct = 0; ct < 8; ++ct) {
        unsigned short u[4];
#pragma unroll
        for (int i = 0; i < 4; ++i) {
          __hip_bfloat16 b = __float2bfloat16(acc[ct][i]);
          u[i] = *reinterpret_cast<unsigned short*>(&b);
        }
        *reinterpret_cast<uint2*>(&h[(size_t)r * HC + colbase + ct * 16 + g4 * 4]) =
            *reinterpret_cast<uint2*>(u);
      }
    }

    float ps[2] = {0.f, 0.f};
    float pd[2] = {0.f, 0.f};
#pragma unroll
    for (int ct = 0; ct < 8; ++ct) {
      int hh = ct >> 2;
      int col = colbase + ct * 16 + g4 * 4;
      float4 as4 = *reinterpret_cast<const float4*>(&a_s[col]);
      float4 ad4 = *reinterpret_cast<const float4*>(&a_d[col]);
      ps[hh] += acc[ct][0] * as4.x + acc[ct][1] * as4.y + acc[ct][2] * as4.z + acc[ct][3] * as4.w;
      pd[hh] += acc[ct][0] * ad4.x + acc[ct][1] * ad4.y + acc[ct][2] * ad4.z + acc[ct][3] * ad4.w;
    }
#pragma unroll
    for (int hh = 0; hh < 2; ++hh) {
      ps[hh] += __shfl_xor(ps[hh], 16, 64);
      ps[hh] += __shfl_xor(ps[hh], 32, 64);
      pd[hh] += __shfl_xor(pd[hh], 16, 64);
      pd[hh] += __shfl_xor(pd[hh], 32, 64);
    }
    if (lane < 16 && valid) {
      *reinterpret_cast<float2*>(&asrc_n[(size_t)r * NH + ch * 2]) =
          make_float2(ps[0], ps[1]);
      *reinterpret_cast<float2*>(&adst_n[(size_t)r * NH + ch * 2]) =
          make_float2(pd[0], pd[1]);
    }
  }
}

// ----------------- fused softmax + aggregation: one node per wave -----------------
// Lane l = (slot l>>3, cp l&7): channels cp*8..cp*8+7 in ALL 4 heads.
// Per iter: 8 edges; per lane 1 x 16B asrc gather (slot-broadcast), 4 x 16B h.
// Weights computed in-loop (exp, no max-shift: |logit|<~2, shift-invariant).
// Depth-2 pipeline, no LDS, no barriers. Sentinel-padded ssrc.

__global__ __launch_bounds__(256) void aggregate_kernel(
    const int* __restrict__ row_off, const int* __restrict__ ssrc,
    const __hip_bfloat16* __restrict__ h, const float* __restrict__ asrc_n,
    const float* __restrict__ adst_n, const float* __restrict__ bias,
    __hip_bfloat16* __restrict__ out_bf, float* __restrict__ out_f32, int n_nodes) {
  int n = (blockIdx.x * blockDim.x + threadIdx.x) >> 6;  // global wave id = node
  if (n >= n_nodes) return;
  int l    = threadIdx.x & 63;
  int slot = l >> 3;
  int cp   = l & 7;
  const char* hbase = reinterpret_cast<const char*>(h);
  const float4 z4 = make_float4(0.f, 0.f, 0.f, 0.f);
  const uint4 zu = {0, 0, 0, 0};

  int beg  = row_off[n];
  int deg  = row_off[n + 1] - beg;
  float4 adn = reinterpret_cast<const float4*>(adst_n)[n];

  float facc[32];
#pragma unroll
  for (int u = 0; u < 32; ++u) facc[u] = 0.f;
  float4 ds = z4;

  auto LOADE = [&](int j, float4& a4, float& msk, uint4* d) {
    int jj  = j + slot;
    int idx = beg + jj;               // sentinel-padded: always in-bounds
    int sv  = ssrc[idx];
    a4  = reinterpret_cast<const float4*>(asrc_n)[sv];
    msk = (jj < deg) ? 1.f : 0.f;
    const char* hp = hbase + (size_t)sv * 512 + cp * 16;
    d[0] = *reinterpret_cast<const uint4*>(hp);
    d[1] = *reinterpret_cast<const uint4*>(hp + 128);
    d[2] = *reinterpret_cast<const uint4*>(hp + 256);
    d[3] = *reinterpret_cast<const uint4*>(hp + 384);
  };

  auto PROC = [&](const float4& a4, float msk, const uint4* d) {
    float e0 = a4.x + adn.x; e0 = fmaxf(e0, 0.2f * e0);
    float e1 = a4.y + adn.y; e1 = fmaxf(e1, 0.2f * e1);
    float e2 = a4.z + adn.z; e2 = fmaxf(e2, 0.2f * e2);
    float e3 = a4.w + adn.w; e3 = fmaxf(e3, 0.2f * e3);
    float w0 = __expf(e0) * msk;
    float w1 = __expf(e1) * msk;
    float w2 = __expf(e2) * msk;
    float w3 = __expf(e3) * msk;
    ds.x += w0; ds.y += w1; ds.z += w2; ds.w += w3;
#pragma unroll
    for (int hh = 0; hh < 4; ++hh) {
      float w = (hh == 0) ? w0 : (hh == 1) ? w1 : (hh == 2) ? w2 : w3;
      uint4 dd = d[hh];
      facc[hh * 8 + 0] += w * __uint_as_float(dd.x << 16);
      facc[hh * 8 + 1] += w * __uint_as_float(dd.x & 0xffff0000u);
      facc[hh * 8 + 2] += w * __uint_as_float(dd.y << 16);
      facc[hh * 8 + 3] += w * __uint_as_float(dd.y & 0xffff0000u);
      facc[hh * 8 + 4] += w * __uint_as_float(dd.z << 16);
      facc[hh * 8 + 5] += w * __uint_as_float(dd.z & 0xffff0000u);
      facc[hh * 8 + 6] += w * __uint_as_float(dd.w << 16);
      facc[hh * 8 + 7] += w * __uint_as_float(dd.w & 0xffff0000u);
    }
  };

  float4 aA = z4, aB = z4;
  float mA = 0.f, mB = 0.f;
  uint4 dA[4] = {zu, zu, zu, zu};
  uint4 dB[4] = {zu, zu, zu, zu};

  LOADE(0, aA, mA, dA);
  for (int j = 0; j < deg; j += 16) {
    if (j + 8 < deg) LOADE(j + 8, aB, mB, dB); else mB = 0.f;
    PROC(aA, mA, dA);
    if (j + 16 < deg) LOADE(j + 16, aA, mA, dA); else mA = 0.f;
    PROC(aB, mB, dB);
  }

#pragma unroll
  for (int o = 8; o <= 32; o <<= 1) {
    ds.x += __shfl_xor(ds.x, o, 64);
    ds.y += __shfl_xor(ds.y, o, 64);
    ds.z += __shfl_xor(ds.z, o, 64);
    ds.w += __shfl_xor(ds.w, o, 64);
  }
  float iv0 = 1.f / (ds.x + 1e-16f);
  float iv1 = 1.f / (ds.y + 1e-16f);
  float iv2 = 1.f / (ds.z + 1e-16f);
  float iv3 = 1.f / (ds.w + 1e-16f);

  float v[8];
#pragma unroll
  for (int u = 0; u < 8; ++u)
    v[u] = facc[u] * iv0 + facc[8 + u] * iv1 + facc[16 + u] * iv2 + facc[24 + u] * iv3;

#pragma unroll
  for (int u = 0; u < 8; ++u) {
    v[u] += __shfl_xor(v[u], 8, 64);
    v[u] += __shfl_xor(v[u], 16, 64);
    v[u] += __shfl_xor(v[u], 32, 64);
  }

  if (slot < 2) {  // lane (slot, cp) writes channels cp*8 + slot*4 .. +3
    float o0 = (slot == 0) ? v[0] : v[4];
    float o1 = (slot == 0) ? v[1] : v[5];
    float o2 = (slot == 0) ? v[2] : v[6];
    float o3 = (slot == 0) ? v[3] : v[7];
    int chn = cp * 8 + slot * 4;
    float4 b4 = *reinterpret_cast<const float4*>(&bias[chn]);
    o0 = fmaxf(0.25f * o0 + b4.x, 0.f);
    o1 = fmaxf(0.25f * o1 + b4.y, 0.f);
    o2 = fmaxf(0.25f * o2 + b4.z, 0.f);
    o3 = fmaxf(0.25f * o3 + b4.w, 0.f);
    if (out_f32) {
      *reinterpret_cast<float4*>(&out_f32[(size_t)n * CHID + chn]) =
          make_float4(o0, o1, o2, o3);
    } else {
      float of[4] = {o0, o1, o2, o3};
      unsigned short b16[4];
#pragma unroll
      for (int u = 0; u < 4; ++u) {
        __hip_bfloat16 bh = __float2bfloat16(of[u]);
        b16[u] = *reinterpret_cast<unsigned short*>(&bh);
      }
      *reinterpret_cast<uint2*>(&out_bf[(size_t)n * CHID + chn]) =
          *reinterpret_cast<uint2*>(b16);
    }
  }
}

// ----------------- launch -----------------

extern "C" void kernel_launch(void* const* d_in, const int* in_sizes, int n_in,
                              void* d_out, int out_size, void* d_ws, size_t ws_size,
                              hipStream_t stream) {
  const float* x   = (const float*)d_in[0];
  const int*   ei  = (const int*)d_in[1];
  const float* W1  = (const float*)d_in[2];
  const float* as1 = (const float*)d_in[3];
  const float* ad1 = (const float*)d_in[4];
  const float* b1  = (const float*)d_in[5];
  const float* W2  = (const float*)d_in[6];
  const float* as2 = (const float*)d_in[7];
  const float* ad2 = (const float*)d_in[8];
  const float* b2  = (const float*)d_in[9];
  const float* W3  = (const float*)d_in[10];
  const float* as3 = (const float*)d_in[11];
  const float* ad3 = (const float*)d_in[12];
  const float* b3  = (const float*)d_in[13];

  int N  = in_sizes[0] / 128;
  int E  = in_sizes[1] / 2;
  int EP = E + N;
  int NB = (N + 255) / 256;  // scan chunks

  // workspace carve-up (all 16B-aligned)
  __hip_bfloat16* h    = (__hip_bfloat16*)d_ws;         // N*256
  __hip_bfloat16* x1b  = h + (size_t)N * HC;            // N*128
  __hip_bfloat16* xb   = x1b + (size_t)N * 128;         // N*64
  __hip_bfloat16* w1b  = xb + (size_t)N * CHID;         // 256*128
  __hip_bfloat16* w2b  = w1b + 256 * 128;               // 256*64
  __hip_bfloat16* w3b  = w2b + 256 * 64;                // 256*64
  float* asrc_n = (float*)(w3b + 256 * 64);             // N*4
  float* adst_n = asrc_n + (size_t)N * NH;              // N*4
  int*   deg    = (int*)(adst_n + (size_t)N * NH);      // N
  int*   cursor = deg + N;                              // N
  int*   row_off= cursor + N;                           // N+1
  int*   part   = row_off + (N + 1);                    // NB
  int*   ssrc   = part + ((NB + 3) & ~3);               // EP+8

  hipMemsetAsync(deg, 0, sizeof(int) * (size_t)2 * N, stream);  // deg + cursor
  int eb = (EP + 8 + 255) / 256;
  hist_kernel<<<eb, 256, 0, stream>>>(ei, E, N, deg);
  partial_sum_kernel<<<NB, 256, 0, stream>>>(deg, part, N);
  scan_part_kernel<<<1, 256, 0, stream>>>(part, NB, row_off, N);
  row_off_kernel<<<NB, 256, 0, stream>>>(deg, part, row_off, N);
  scatter_kernel<<<eb, 256, 0, stream>>>(ei, E, N, row_off, cursor, ssrc);

  int n4 = N * 128 / 4;
  prep_kernel<<<(n4 + 65536 + 255) / 256, 256, 0, stream>>>(x, x1b, n4,
                                                            W1, W2, W3, w1b, w2b, w3b);

  (void)hipFuncSetAttribute(reinterpret_cast<const void*>(&gemm_mfma_kernel<128>),
                            hipFuncAttributeMaxDynamicSharedMemorySize, 65536);
  (void)hipFuncSetAttribute(reinterpret_cast<const void*>(&gemm_mfma_kernel<64>),
                            hipFuncAttributeMaxDynamicSharedMemorySize, 65536);

  int RG = (N + 63) / 64;         // 64-row groups (782)
  dim3 ggrid((RG + 1) / 2, 2);    // each block: stage W once, 2 groups preloaded
  int ablocks = (N + 3) / 4;      // one node per wave, 4 waves per block

  // layer 1 (K=128, LDS 32KB/block)
  gemm_mfma_kernel<128><<<ggrid, 256, 32768, stream>>>(x1b, w1b, as1, ad1,
                                                       h, asrc_n, adst_n, N, RG);
  aggregate_kernel<<<ablocks, 256, 0, stream>>>(row_off, ssrc, h, asrc_n, adst_n, b1,
                                                xb, nullptr, N);
  // layer 2 (K=64, LDS 16KB/block)
  gemm_mfma_kernel<64><<<ggrid, 256, 16384, stream>>>(xb, w2b, as2, ad2,
                                                      h, asrc_n, adst_n, N, RG);
  aggregate_kernel<<<ablocks, 256, 0, stream>>>(row_off, ssrc, h, asrc_n, adst_n, b2,
                                                xb, nullptr, N);
  // layer 3 (K=64)
  gemm_mfma_kernel<64><<<ggrid, 256, 16384, stream>>>(xb, w3b, as3, ad3,
                                                      h, asrc_n, adst_n, N, RG);
  aggregate_kernel<<<ablocks, 256, 0, stream>>>(row_off, ssrc, h, asrc_n, adst_n, b3,
                                                nullptr, (float*)d_out, N);
}

// Round 15
// 351.718 us; speedup vs baseline: 1.0594x; 1.0594x over previous
//
#include <hip/hip_runtime.h>
#include <hip/hip_bf16.h>
#include <cstddef>

#define NH 4
#define CHID 64
#define HC 256  // NH*CHID

typedef __attribute__((ext_vector_type(8))) short bf16x8;
typedef __attribute__((ext_vector_type(4))) float f32x4;

// ----------------- counting sort by dst (CSR build) -----------------

__global__ void hist_kernel(const int* __restrict__ ei, int E, int N,
                            int* __restrict__ deg) {
  int i = blockIdx.x * blockDim.x + threadIdx.x;
  int EP = E + N;
  if (i >= EP) return;
  int d = (i < E) ? ei[E + i] : (i - E);  // self-loop tail: node i-E
  atomicAdd(&deg[d], 1);
}

__global__ __launch_bounds__(256) void partial_sum_kernel(const int* __restrict__ deg,
                                                          int* __restrict__ part, int n) {
  __shared__ int red[4];
  int t = threadIdx.x;
  int i = blockIdx.x * 256 + t;
  int v = (i < n) ? deg[i] : 0;
#pragma unroll
  for (int o = 32; o; o >>= 1) v += __shfl_xor(v, o, 64);
  if ((t & 63) == 0) red[t >> 6] = v;
  __syncthreads();
  if (t == 0) part[blockIdx.x] = red[0] + red[1] + red[2] + red[3];
}

__global__ __launch_bounds__(256) void scan_part_kernel(int* __restrict__ part, int nb,
                                                        int* __restrict__ row_off, int n) {
  __shared__ int s[256];
  int t = threadIdx.x;
  int v = (t < nb) ? part[t] : 0;
  s[t] = v;
  __syncthreads();
  for (int o = 1; o < 256; o <<= 1) {
    int u = (t >= o) ? s[t - o] : 0;
    __syncthreads();
    s[t] += u;
    __syncthreads();
  }
  if (t < nb) part[t] = s[t] - v;        // exclusive base per chunk
  if (t == 255) row_off[n] = s[255];     // grand total
}

__global__ __launch_bounds__(256) void row_off_kernel(const int* __restrict__ deg,
                                                      const int* __restrict__ part,
                                                      int* __restrict__ row_off, int n) {
  __shared__ int s[256];
  int t = threadIdx.x;
  int i = blockIdx.x * 256 + t;
  int v = (i < n) ? deg[i] : 0;
  s[t] = v;
  __syncthreads();
  for (int o = 1; o < 256; o <<= 1) {
    int u = (t >= o) ? s[t - o] : 0;
    __syncthreads();
    s[t] += u;
    __syncthreads();
  }
  if (i < n) row_off[i] = part[blockIdx.x] + s[t] - v;
}

__global__ void scatter_kernel(const int* __restrict__ ei, int E, int N,
                               const int* __restrict__ row_off,
                               int* __restrict__ cursor, int* __restrict__ ssrc) {
  int i = blockIdx.x * blockDim.x + threadIdx.x;
  int EP = E + N;
  if (i >= EP) {
    if (i < EP + 8) ssrc[i] = 0;  // sentinel pad
    return;
  }
  int s, d;
  if (i < E) { s = ei[i]; d = ei[E + i]; } else { s = i - E; d = s; }
  int pos = row_off[d] + atomicAdd(&cursor[d], 1);
  ssrc[pos] = s;
}

// ----------------- prep: x -> bf16, W1/2/3 -> transposed bf16 -----------------

__global__ void prep_kernel(const float* __restrict__ x,
                            __hip_bfloat16* __restrict__ xb, int n4,
                            const float* __restrict__ W1, const float* __restrict__ W2,
                            const float* __restrict__ W3,
                            __hip_bfloat16* __restrict__ w1b,
                            __hip_bfloat16* __restrict__ w2b,
                            __hip_bfloat16* __restrict__ w3b) {
  int i = blockIdx.x * blockDim.x + threadIdx.x;
  if (i < n4) {
    float4 v = reinterpret_cast<const float4*>(x)[i];
    __hip_bfloat16 h[4] = {__float2bfloat16(v.x), __float2bfloat16(v.y),
                           __float2bfloat16(v.z), __float2bfloat16(v.w)};
    reinterpret_cast<uint2*>(xb)[i] = *reinterpret_cast<uint2*>(h);
    return;
  }
  int j = i - n4;
  if (j >= 65536) return;
  const float* W; __hip_bfloat16* wb; int K, base;
  if (j < 32768)      { W = W1; wb = w1b; K = 128; base = j; }
  else if (j < 49152) { W = W2; wb = w2b; K = 64;  base = j - 32768; }
  else                { W = W3; wb = w3b; K = 64;  base = j - 49152; }
  int k = base >> 8;
  int c = base & 255;
  wb[c * K + k] = __float2bfloat16(W[base]);
}

// ----------------- MFMA bf16 GEMM, col-split, W in LDS (r13 form) -----------------
// blockIdx.y = col-half ch: output cols [ch*128, ch*128+128) = heads {2ch, 2ch+1}.
// grid.x = ceil(RG/2): each block stages W ONCE and loops 2 row-groups (no
// barrier in the loop -> compiler overlaps next group's x-loads with MFMAs).

template <int K>
__global__ __launch_bounds__(256) void gemm_mfma_kernel(
    const __hip_bfloat16* __restrict__ Ab,
    const __hip_bfloat16* __restrict__ Btb,
    const float* __restrict__ a_s, const float* __restrict__ a_d,
    __hip_bfloat16* __restrict__ h, float* __restrict__ asrc_n,
    float* __restrict__ adst_n, int n_rows, int row_groups) {
  extern __shared__ char smem[];
  uint4* lds4 = reinterpret_cast<uint4*>(smem);
  constexpr int KS = K / 32;                 // k0 steps
  constexpr int S16 = (128 * K * 2) >> 4;    // 16B chunks (128 W rows)
  constexpr int rowshift = (K == 128) ? 4 : 3;
  int ch = blockIdx.y;                       // col half (0/1)
  int colbase = ch * 128;

  {
    const uint4* g = reinterpret_cast<const uint4*>(Btb + (size_t)colbase * K);
    for (int c = threadIdx.x; c < S16; c += 256) {
      int row = c >> rowshift;
      lds4[c ^ (row & 7)] = g[c];
    }
  }
  __syncthreads();

  int wave = threadIdx.x >> 6;
  int lane = threadIdx.x & 63;
  int n16  = lane & 15;
  int g4   = lane >> 4;
  const bf16x8 z8 = {0, 0, 0, 0, 0, 0, 0, 0};

  for (int gg = blockIdx.x; gg < row_groups; gg += gridDim.x) {
    int row0 = gg * 64 + wave * 16;
    int xrow = row0 + n16;
    bool aval = xrow < n_rows;
    size_t xbase = (size_t)xrow * K + g4 * 8;

    bf16x8 xh[KS];
#pragma unroll
    for (int s = 0; s < KS; ++s)
      xh[s] = aval ? *reinterpret_cast<const bf16x8*>(&Ab[xbase + s * 32]) : z8;

    f32x4 acc[8];
#pragma unroll
    for (int ct = 0; ct < 8; ++ct) acc[ct] = (f32x4){0.f, 0.f, 0.f, 0.f};

#pragma unroll
    for (int ct = 0; ct < 8; ++ct) {
      int wrow = ct * 16 + n16;  // local W row (0..127)
#pragma unroll
      for (int s = 0; s < KS; ++s) {
        int ci = ((wrow * K + s * 32 + g4 * 8) >> 3) ^ (wrow & 7);
        bf16x8 wh = *reinterpret_cast<const bf16x8*>(&lds4[ci]);
        acc[ct] = __builtin_amdgcn_mfma_f32_16x16x32_bf16(wh, xh[s], acc[ct], 0, 0, 0);
      }
    }

    int r = row0 + n16;
    bool valid = r < n_rows;

    if (valid) {
#pragma unroll
      for (int ct = 0; ct < 8; ++ct) {
        unsigned short u[4];
#pragma unroll
        for (int i = 0; i < 4; ++i) {
          __hip_bfloat16 b = __float2bfloat16(acc[ct][i]);
          u[i] = *reinterpret_cast<unsigned short*>(&b);
        }
        *reinterpret_cast<uint2*>(&h[(size_t)r * HC + colbase + ct * 16 + g4 * 4]) =
            *reinterpret_cast<uint2*>(u);
      }
    }

    float ps[2] = {0.f, 0.f};
    float pd[2] = {0.f, 0.f};
#pragma unroll
    for (int ct = 0; ct < 8; ++ct) {
      int hh = ct >> 2;
      int col = colbase + ct * 16 + g4 * 4;
      float4 as4 = *reinterpret_cast<const float4*>(&a_s[col]);
      float4 ad4 = *reinterpret_cast<const float4*>(&a_d[col]);
      ps[hh] += acc[ct][0] * as4.x + acc[ct][1] * as4.y + acc[ct][2] * as4.z + acc[ct][3] * as4.w;
      pd[hh] += acc[ct][0] * ad4.x + acc[ct][1] * ad4.y + acc[ct][2] * ad4.z + acc[ct][3] * ad4.w;
    }
#pragma unroll
    for (int hh = 0; hh < 2; ++hh) {
      ps[hh] += __shfl_xor(ps[hh], 16, 64);
      ps[hh] += __shfl_xor(ps[hh], 32, 64);
      pd[hh] += __shfl_xor(pd[hh], 16, 64);
      pd[hh] += __shfl_xor(pd[hh], 32, 64);
    }
    if (lane < 16 && valid) {
      *reinterpret_cast<float2*>(&asrc_n[(size_t)r * NH + ch * 2]) =
          make_float2(ps[0], ps[1]);
      *reinterpret_cast<float2*>(&adst_n[(size_t)r * NH + ch * 2]) =
          make_float2(pd[0], pd[1]);
    }
  }
}

// ----------------- fused softmax + aggregation: one node per wave -----------------
// Lane l = (slot l>>3, cp l&7): channels cp*8..cp*8+7 in ALL 4 heads.
// NEW: masked slots SKIP their loads (uniform per 8-lane slot group; exec-masked
// requests issue no memory traffic) — avg deg 17 means 8*ceil(deg/8) ~ 21.6
// slots touched, so unconditional loads wasted ~20% of gather bandwidth.
// Stale registers are harmless: multiplied by w=0, always finite.

__global__ __launch_bounds__(256) void aggregate_kernel(
    const int* __restrict__ row_off, const int* __restrict__ ssrc,
    const __hip_bfloat16* __restrict__ h, const float* __restrict__ asrc_n,
    const float* __restrict__ adst_n, const float* __restrict__ bias,
    __hip_bfloat16* __restrict__ out_bf, float* __restrict__ out_f32, int n_nodes) {
  int n = (blockIdx.x * blockDim.x + threadIdx.x) >> 6;  // global wave id = node
  if (n >= n_nodes) return;
  int l    = threadIdx.x & 63;
  int slot = l >> 3;
  int cp   = l & 7;
  const char* hbase = reinterpret_cast<const char*>(h);
  const float4 z4 = make_float4(0.f, 0.f, 0.f, 0.f);
  const uint4 zu = {0, 0, 0, 0};

  int beg  = row_off[n];
  int deg  = row_off[n + 1] - beg;
  float4 adn = reinterpret_cast<const float4*>(adst_n)[n];

  float facc[32];
#pragma unroll
  for (int u = 0; u < 32; ++u) facc[u] = 0.f;
  float4 ds = z4;

  auto LOADE = [&](int j, float4& a4, float& msk, uint4* d) {
    int jj = j + slot;
    if (jj < deg) {                   // uniform per slot group: masked slots
      int idx = beg + jj;             // issue NO memory requests
      int sv  = ssrc[idx];
      a4  = reinterpret_cast<const float4*>(asrc_n)[sv];
      msk = 1.f;
      const char* hp = hbase + (size_t)sv * 512 + cp * 16;
      d[0] = *reinterpret_cast<const uint4*>(hp);
      d[1] = *reinterpret_cast<const uint4*>(hp + 128);
      d[2] = *reinterpret_cast<const uint4*>(hp + 256);
      d[3] = *reinterpret_cast<const uint4*>(hp + 384);
    } else {
      msk = 0.f;
    }
  };

  auto PROC = [&](const float4& a4, float msk, const uint4* d) {
    float e0 = a4.x + adn.x; e0 = fmaxf(e0, 0.2f * e0);
    float e1 = a4.y + adn.y; e1 = fmaxf(e1, 0.2f * e1);
    float e2 = a4.z + adn.z; e2 = fmaxf(e2, 0.2f * e2);
    float e3 = a4.w + adn.w; e3 = fmaxf(e3, 0.2f * e3);
    float w0 = __expf(e0) * msk;
    float w1 = __expf(e1) * msk;
    float w2 = __expf(e2) * msk;
    float w3 = __expf(e3) * msk;
    ds.x += w0; ds.y += w1; ds.z += w2; ds.w += w3;
#pragma unroll
    for (int hh = 0; hh < 4; ++hh) {
      float w = (hh == 0) ? w0 : (hh == 1) ? w1 : (hh == 2) ? w2 : w3;
      uint4 dd = d[hh];
      facc[hh * 8 + 0] += w * __uint_as_float(dd.x << 16);
      facc[hh * 8 + 1] += w * __uint_as_float(dd.x & 0xffff0000u);
      facc[hh * 8 + 2] += w * __uint_as_float(dd.y << 16);
      facc[hh * 8 + 3] += w * __uint_as_float(dd.y & 0xffff0000u);
      facc[hh * 8 + 4] += w * __uint_as_float(dd.z << 16);
      facc[hh * 8 + 5] += w * __uint_as_float(dd.z & 0xffff0000u);
      facc[hh * 8 + 6] += w * __uint_as_float(dd.w << 16);
      facc[hh * 8 + 7] += w * __uint_as_float(dd.w & 0xffff0000u);
    }
  };

  float4 aA = z4, aB = z4;
  float mA = 0.f, mB = 0.f;
  uint4 dA[4] = {zu, zu, zu, zu};
  uint4 dB[4] = {zu, zu, zu, zu};

  LOADE(0, aA, mA, dA);
  for (int j = 0; j < deg; j += 16) {
    if (j + 8 < deg) LOADE(j + 8, aB, mB, dB); else mB = 0.f;
    PROC(aA, mA, dA);
    if (j + 16 < deg) LOADE(j + 16, aA, mA, dA); else mA = 0.f;
    PROC(aB, mB, dB);
  }

#pragma unroll
  for (int o = 8; o <= 32; o <<= 1) {
    ds.x += __shfl_xor(ds.x, o, 64);
    ds.y += __shfl_xor(ds.y, o, 64);
    ds.z += __shfl_xor(ds.z, o, 64);
    ds.w += __shfl_xor(ds.w, o, 64);
  }
  float iv0 = 1.f / (ds.x + 1e-16f);
  float iv1 = 1.f / (ds.y + 1e-16f);
  float iv2 = 1.f / (ds.z + 1e-16f);
  float iv3 = 1.f / (ds.w + 1e-16f);

  float v[8];
#pragma unroll
  for (int u = 0; u < 8; ++u)
    v[u] = facc[u] * iv0 + facc[8 + u] * iv1 + facc[16 + u] * iv2 + facc[24 + u] * iv3;

#pragma unroll
  for (int u = 0; u < 8; ++u) {
    v[u] += __shfl_xor(v[u], 8, 64);
    v[u] += __shfl_xor(v[u], 16, 64);
    v[u] += __shfl_xor(v[u], 32, 64);
  }

  if (slot < 2) {  // lane (slot, cp) writes channels cp*8 + slot*4 .. +3
    float o0 = (slot == 0) ? v[0] : v[4];
    float o1 = (slot == 0) ? v[1] : v[5];
    float o2 = (slot == 0) ? v[2] : v[6];
    float o3 = (slot == 0) ? v[3] : v[7];
    int chn = cp * 8 + slot * 4;
    float4 b4 = *reinterpret_cast<const float4*>(&bias[chn]);
    o0 = fmaxf(0.25f * o0 + b4.x, 0.f);
    o1 = fmaxf(0.25f * o1 + b4.y, 0.f);
    o2 = fmaxf(0.25f * o2 + b4.z, 0.f);
    o3 = fmaxf(0.25f * o3 + b4.w, 0.f);
    if (out_f32) {
      *reinterpret_cast<float4*>(&out_f32[(size_t)n * CHID + chn]) =
          make_float4(o0, o1, o2, o3);
    } else {
      float of[4] = {o0, o1, o2, o3};
      unsigned short b16[4];
#pragma unroll
      for (int u = 0; u < 4; ++u) {
        __hip_bfloat16 bh = __float2bfloat16(of[u]);
        b16[u] = *reinterpret_cast<unsigned short*>(&bh);
      }
      *reinterpret_cast<uint2*>(&out_bf[(size_t)n * CHID + chn]) =
          *reinterpret_cast<uint2*>(b16);
    }
  }
}

// ----------------- launch -----------------

extern "C" void kernel_launch(void* const* d_in, const int* in_sizes, int n_in,
                              void* d_out, int out_size, void* d_ws, size_t ws_size,
                              hipStream_t stream) {
  const float* x   = (const float*)d_in[0];
  const int*   ei  = (const int*)d_in[1];
  const float* W1  = (const float*)d_in[2];
  const float* as1 = (const float*)d_in[3];
  const float* ad1 = (const float*)d_in[4];
  const float* b1  = (const float*)d_in[5];
  const float* W2  = (const float*)d_in[6];
  const float* as2 = (const float*)d_in[7];
  const float* ad2 = (const float*)d_in[8];
  const float* b2  = (const float*)d_in[9];
  const float* W3  = (const float*)d_in[10];
  const float* as3 = (const float*)d_in[11];
  const float* ad3 = (const float*)d_in[12];
  const float* b3  = (const float*)d_in[13];

  int N  = in_sizes[0] / 128;
  int E  = in_sizes[1] / 2;
  int EP = E + N;
  int NB = (N + 255) / 256;  // scan chunks

  // workspace carve-up (all 16B-aligned)
  __hip_bfloat16* h    = (__hip_bfloat16*)d_ws;         // N*256
  __hip_bfloat16* x1b  = h + (size_t)N * HC;            // N*128
  __hip_bfloat16* xb   = x1b + (size_t)N * 128;         // N*64
  __hip_bfloat16* w1b  = xb + (size_t)N * CHID;         // 256*128
  __hip_bfloat16* w2b  = w1b + 256 * 128;               // 256*64
  __hip_bfloat16* w3b  = w2b + 256 * 64;                // 256*64
  float* asrc_n = (float*)(w3b + 256 * 64);             // N*4
  float* adst_n = asrc_n + (size_t)N * NH;              // N*4
  int*   deg    = (int*)(adst_n + (size_t)N * NH);      // N
  int*   cursor = deg + N;                              // N
  int*   row_off= cursor + N;                           // N+1
  int*   part   = row_off + (N + 1);                    // NB
  int*   ssrc   = part + ((NB + 3) & ~3);               // EP+8

  hipMemsetAsync(deg, 0, sizeof(int) * (size_t)2 * N, stream);  // deg + cursor
  int eb = (EP + 8 + 255) / 256;
  hist_kernel<<<eb, 256, 0, stream>>>(ei, E, N, deg);
  partial_sum_kernel<<<NB, 256, 0, stream>>>(deg, part, N);
  scan_part_kernel<<<1, 256, 0, stream>>>(part, NB, row_off, N);
  row_off_kernel<<<NB, 256, 0, stream>>>(deg, part, row_off, N);
  scatter_kernel<<<eb, 256, 0, stream>>>(ei, E, N, row_off, cursor, ssrc);

  int n4 = N * 128 / 4;
  prep_kernel<<<(n4 + 65536 + 255) / 256, 256, 0, stream>>>(x, x1b, n4,
                                                            W1, W2, W3, w1b, w2b, w3b);

  (void)hipFuncSetAttribute(reinterpret_cast<const void*>(&gemm_mfma_kernel<128>),
                            hipFuncAttributeMaxDynamicSharedMemorySize, 65536);
  (void)hipFuncSetAttribute(reinterpret_cast<const void*>(&gemm_mfma_kernel<64>),
                            hipFuncAttributeMaxDynamicSharedMemorySize, 65536);

  int RG = (N + 63) / 64;         // 64-row groups (782)
  dim3 ggrid((RG + 1) / 2, 2);    // each block stages W once, loops 2 groups
  int ablocks = (N + 3) / 4;      // one node per wave, 4 waves per block

  // layer 1 (K=128, LDS 32KB/block)
  gemm_mfma_kernel<128><<<ggrid, 256, 32768, stream>>>(x1b, w1b, as1, ad1,
                                                       h, asrc_n, adst_n, N, RG);
  aggregate_kernel<<<ablocks, 256, 0, stream>>>(row_off, ssrc, h, asrc_n, adst_n, b1,
                                                xb, nullptr, N);
  // layer 2 (K=64, LDS 16KB/block)
  gemm_mfma_kernel<64><<<ggrid, 256, 16384, stream>>>(xb, w2b, as2, ad2,
                                                      h, asrc_n, adst_n, N, RG);
  aggregate_kernel<<<ablocks, 256, 0, stream>>>(row_off, ssrc, h, asrc_n, adst_n, b2,
                                                xb, nullptr, N);
  // layer 3 (K=64)
  gemm_mfma_kernel<64><<<ggrid, 256, 16384, stream>>>(xb, w3b, as3, ad3,
                                                      h, asrc_n, adst_n, N, RG);
  aggregate_kernel<<<ablocks, 256, 0, stream>>>(row_off, ssrc, h, asrc_n, adst_n, b3,
                                                nullptr, (float*)d_out, N);
}

// Round 16
// 348.489 us; speedup vs baseline: 1.0692x; 1.0093x over previous
//
#include <hip/hip_runtime.h>
#include <hip/hip_bf16.h>
#include <cstddef>

#define NH 4
#define CHID 64
#define HC 256  // NH*CHID

typedef __attribute__((ext_vector_type(8))) short bf16x8;
typedef __attribute__((ext_vector_type(4))) float f32x4;

// ----------------- counting sort by dst (CSR build) -----------------

__global__ void hist_kernel(const int* __restrict__ ei, int E, int N,
                            int* __restrict__ deg) {
  int i = blockIdx.x * blockDim.x + threadIdx.x;
  int EP = E + N;
  if (i >= EP) return;
  int d = (i < E) ? ei[E + i] : (i - E);  // self-loop tail: node i-E
  atomicAdd(&deg[d], 1);
}

__global__ __launch_bounds__(256) void partial_sum_kernel(const int* __restrict__ deg,
                                                          int* __restrict__ part, int n) {
  __shared__ int red[4];
  int t = threadIdx.x;
  int i = blockIdx.x * 256 + t;
  int v = (i < n) ? deg[i] : 0;
#pragma unroll
  for (int o = 32; o; o >>= 1) v += __shfl_xor(v, o, 64);
  if ((t & 63) == 0) red[t >> 6] = v;
  __syncthreads();
  if (t == 0) part[blockIdx.x] = red[0] + red[1] + red[2] + red[3];
}

__global__ __launch_bounds__(256) void scan_part_kernel(int* __restrict__ part, int nb,
                                                        int* __restrict__ row_off, int n) {
  __shared__ int s[256];
  int t = threadIdx.x;
  int v = (t < nb) ? part[t] : 0;
  s[t] = v;
  __syncthreads();
  for (int o = 1; o < 256; o <<= 1) {
    int u = (t >= o) ? s[t - o] : 0;
    __syncthreads();
    s[t] += u;
    __syncthreads();
  }
  if (t < nb) part[t] = s[t] - v;        // exclusive base per chunk
  if (t == 255) row_off[n] = s[255];     // grand total
}

__global__ __launch_bounds__(256) void row_off_kernel(const int* __restrict__ deg,
                                                      const int* __restrict__ part,
                                                      int* __restrict__ row_off, int n) {
  __shared__ int s[256];
  int t = threadIdx.x;
  int i = blockIdx.x * 256 + t;
  int v = (i < n) ? deg[i] : 0;
  s[t] = v;
  __syncthreads();
  for (int o = 1; o < 256; o <<= 1) {
    int u = (t >= o) ? s[t - o] : 0;
    __syncthreads();
    s[t] += u;
    __syncthreads();
  }
  if (i < n) row_off[i] = part[blockIdx.x] + s[t] - v;
}

__global__ void scatter_kernel(const int* __restrict__ ei, int E, int N,
                               const int* __restrict__ row_off,
                               int* __restrict__ cursor, int* __restrict__ ssrc) {
  int i = blockIdx.x * blockDim.x + threadIdx.x;
  int EP = E + N;
  if (i >= EP) {
    if (i < EP + 8) ssrc[i] = 0;  // sentinel pad
    return;
  }
  int s, d;
  if (i < E) { s = ei[i]; d = ei[E + i]; } else { s = i - E; d = s; }
  int pos = row_off[d] + atomicAdd(&cursor[d], 1);
  ssrc[pos] = s;
}

// ----------------- prep: x -> bf16, W1/2/3 -> transposed bf16 -----------------

__global__ void prep_kernel(const float* __restrict__ x,
                            __hip_bfloat16* __restrict__ xb, int n4,
                            const float* __restrict__ W1, const float* __restrict__ W2,
                            const float* __restrict__ W3,
                            __hip_bfloat16* __restrict__ w1b,
                            __hip_bfloat16* __restrict__ w2b,
                            __hip_bfloat16* __restrict__ w3b) {
  int i = blockIdx.x * blockDim.x + threadIdx.x;
  if (i < n4) {
    float4 v = reinterpret_cast<const float4*>(x)[i];
    __hip_bfloat16 h[4] = {__float2bfloat16(v.x), __float2bfloat16(v.y),
                           __float2bfloat16(v.z), __float2bfloat16(v.w)};
    reinterpret_cast<uint2*>(xb)[i] = *reinterpret_cast<uint2*>(h);
    return;
  }
  int j = i - n4;
  if (j >= 65536) return;
  const float* W; __hip_bfloat16* wb; int K, base;
  if (j < 32768)      { W = W1; wb = w1b; K = 128; base = j; }
  else if (j < 49152) { W = W2; wb = w2b; K = 64;  base = j - 32768; }
  else                { W = W3; wb = w3b; K = 64;  base = j - 49152; }
  int k = base >> 8;
  int c = base & 255;
  wb[c * K + k] = __float2bfloat16(W[base]);
}

// ----------------- MFMA bf16 GEMM, col-split, W in LDS -----------------
// blockIdx.y = col-half ch: output cols [ch*128, ch*128+128) = heads {2ch, 2ch+1}.
// One row-group per block. NEW epilogue: after a barrier the (now-dead) W LDS
// is reused to transpose each wave's 16x256B tile so h is stored as FULL 128B
// lines (old path: 8B/lane scattered stores -> 16 partial lines per instr).

template <int K>
__global__ __launch_bounds__(256) void gemm_mfma_kernel(
    const __hip_bfloat16* __restrict__ Ab,
    const __hip_bfloat16* __restrict__ Btb,
    const float* __restrict__ a_s, const float* __restrict__ a_d,
    __hip_bfloat16* __restrict__ h, float* __restrict__ asrc_n,
    float* __restrict__ adst_n, int n_rows, int row_groups) {
  extern __shared__ char smem[];
  uint4* lds4 = reinterpret_cast<uint4*>(smem);
  constexpr int KS = K / 32;                 // k0 steps
  constexpr int S16 = (128 * K * 2) >> 4;    // 16B chunks (128 W rows)
  constexpr int rowshift = (K == 128) ? 4 : 3;
  int ch = blockIdx.y;                       // col half (0/1)
  int colbase = ch * 128;

  {
    const uint4* g = reinterpret_cast<const uint4*>(Btb + (size_t)colbase * K);
    for (int c = threadIdx.x; c < S16; c += 256) {
      int row = c >> rowshift;
      lds4[c ^ (row & 7)] = g[c];
    }
  }
  __syncthreads();

  int wave = threadIdx.x >> 6;
  int lane = threadIdx.x & 63;
  int n16  = lane & 15;
  int g4   = lane >> 4;
  const bf16x8 z8 = {0, 0, 0, 0, 0, 0, 0, 0};

  int gg = blockIdx.x;
  int row0 = gg * 64 + wave * 16;
  int xrow = row0 + n16;
  bool aval = xrow < n_rows;
  size_t xbase = (size_t)xrow * K + g4 * 8;

  bf16x8 xh[KS];
#pragma unroll
  for (int s = 0; s < KS; ++s)
    xh[s] = aval ? *reinterpret_cast<const bf16x8*>(&Ab[xbase + s * 32]) : z8;

  f32x4 acc[8];
#pragma unroll
  for (int ct = 0; ct < 8; ++ct) acc[ct] = (f32x4){0.f, 0.f, 0.f, 0.f};

#pragma unroll
  for (int ct = 0; ct < 8; ++ct) {
    int wrow = ct * 16 + n16;  // local W row (0..127)
#pragma unroll
    for (int s = 0; s < KS; ++s) {
      int ci = ((wrow * K + s * 32 + g4 * 8) >> 3) ^ (wrow & 7);
      bf16x8 wh = *reinterpret_cast<const bf16x8*>(&lds4[ci]);
      acc[ct] = __builtin_amdgcn_mfma_f32_16x16x32_bf16(wh, xh[s], acc[ct], 0, 0, 0);
    }
  }

  // pack bf16 results (4 cols per ct) while W is still live
  uint2 uval[8];
#pragma unroll
  for (int ct = 0; ct < 8; ++ct) {
    unsigned short u[4];
#pragma unroll
    for (int i = 0; i < 4; ++i) {
      __hip_bfloat16 b = __float2bfloat16(acc[ct][i]);
      u[i] = *reinterpret_cast<unsigned short*>(&b);
    }
    uval[ct] = *reinterpret_cast<uint2*>(u);
  }

  __syncthreads();  // all waves done reading W -> safe to reuse LDS

  // stage wave-private 16x256B tile (XOR-swizzled: write banks 16-way -> ~2-way)
  char* epi = smem + wave * 4096;
#pragma unroll
  for (int ct = 0; ct < 8; ++ct) {
    int boff = (n16 * 256 + ct * 32 + g4 * 8) ^ ((n16 & 7) << 4);
    *reinterpret_cast<uint2*>(epi + boff) = uval[ct];
  }
  // read back row-contiguous, store full 128B lines (8 rows x 128B per instr)
  char* hout = reinterpret_cast<char*>(h);
#pragma unroll
  for (int k = 0; k < 4; ++k) {
    int row = (lane >> 3) + (k & 1) * 8;
    int off = (lane & 7) * 16 + (k >> 1) * 128;
    int lb  = (row * 256 + off) ^ ((row & 7) << 4);
    uint4 v = *reinterpret_cast<uint4*>(epi + lb);
    int r = row0 + row;
    if (r < n_rows)
      *reinterpret_cast<uint4*>(&hout[(size_t)r * 512 + ch * 256 + off]) = v;
  }

  // fused alpha dots (unchanged)
  int r = row0 + n16;
  bool valid = r < n_rows;
  float ps[2] = {0.f, 0.f};
  float pd[2] = {0.f, 0.f};
#pragma unroll
  for (int ct = 0; ct < 8; ++ct) {
    int hh = ct >> 2;
    int col = colbase + ct * 16 + g4 * 4;
    float4 as4 = *reinterpret_cast<const float4*>(&a_s[col]);
    float4 ad4 = *reinterpret_cast<const float4*>(&a_d[col]);
    ps[hh] += acc[ct][0] * as4.x + acc[ct][1] * as4.y + acc[ct][2] * as4.z + acc[ct][3] * as4.w;
    pd[hh] += acc[ct][0] * ad4.x + acc[ct][1] * ad4.y + acc[ct][2] * ad4.z + acc[ct][3] * ad4.w;
  }
#pragma unroll
  for (int hh = 0; hh < 2; ++hh) {
    ps[hh] += __shfl_xor(ps[hh], 16, 64);
    ps[hh] += __shfl_xor(ps[hh], 32, 64);
    pd[hh] += __shfl_xor(pd[hh], 16, 64);
    pd[hh] += __shfl_xor(pd[hh], 32, 64);
  }
  if (lane < 16 && valid) {
    *reinterpret_cast<float2*>(&asrc_n[(size_t)r * NH + ch * 2]) =
        make_float2(ps[0], ps[1]);
    *reinterpret_cast<float2*>(&adst_n[(size_t)r * NH + ch * 2]) =
        make_float2(pd[0], pd[1]);
  }
}

// ----------------- fused softmax + aggregation: one node per wave -----------------
// Lane l = (slot l>>3, cp l&7): channels cp*8..cp*8+7 in ALL 4 heads.
// Masked slots skip their loads (uniform per 8-lane slot group). Depth-2
// pipeline, no LDS, no barriers. Sentinel-padded ssrc.

__global__ __launch_bounds__(256) void aggregate_kernel(
    const int* __restrict__ row_off, const int* __restrict__ ssrc,
    const __hip_bfloat16* __restrict__ h, const float* __restrict__ asrc_n,
    const float* __restrict__ adst_n, const float* __restrict__ bias,
    __hip_bfloat16* __restrict__ out_bf, float* __restrict__ out_f32, int n_nodes) {
  int n = (blockIdx.x * blockDim.x + threadIdx.x) >> 6;  // global wave id = node
  if (n >= n_nodes) return;
  int l    = threadIdx.x & 63;
  int slot = l >> 3;
  int cp   = l & 7;
  const char* hbase = reinterpret_cast<const char*>(h);
  const float4 z4 = make_float4(0.f, 0.f, 0.f, 0.f);
  const uint4 zu = {0, 0, 0, 0};

  int beg  = row_off[n];
  int deg  = row_off[n + 1] - beg;
  float4 adn = reinterpret_cast<const float4*>(adst_n)[n];

  float facc[32];
#pragma unroll
  for (int u = 0; u < 32; ++u) facc[u] = 0.f;
  float4 ds = z4;

  auto LOADE = [&](int j, float4& a4, float& msk, uint4* d) {
    int jj = j + slot;
    if (jj < deg) {
      int idx = beg + jj;
      int sv  = ssrc[idx];
      a4  = reinterpret_cast<const float4*>(asrc_n)[sv];
      msk = 1.f;
      const char* hp = hbase + (size_t)sv * 512 + cp * 16;
      d[0] = *reinterpret_cast<const uint4*>(hp);
      d[1] = *reinterpret_cast<const uint4*>(hp + 128);
      d[2] = *reinterpret_cast<const uint4*>(hp + 256);
      d[3] = *reinterpret_cast<const uint4*>(hp + 384);
    } else {
      msk = 0.f;
    }
  };

  auto PROC = [&](const float4& a4, float msk, const uint4* d) {
    float e0 = a4.x + adn.x; e0 = fmaxf(e0, 0.2f * e0);
    float e1 = a4.y + adn.y; e1 = fmaxf(e1, 0.2f * e1);
    float e2 = a4.z + adn.z; e2 = fmaxf(e2, 0.2f * e2);
    float e3 = a4.w + adn.w; e3 = fmaxf(e3, 0.2f * e3);
    float w0 = __expf(e0) * msk;
    float w1 = __expf(e1) * msk;
    float w2 = __expf(e2) * msk;
    float w3 = __expf(e3) * msk;
    ds.x += w0; ds.y += w1; ds.z += w2; ds.w += w3;
#pragma unroll
    for (int hh = 0; hh < 4; ++hh) {
      float w = (hh == 0) ? w0 : (hh == 1) ? w1 : (hh == 2) ? w2 : w3;
      uint4 dd = d[hh];
      facc[hh * 8 + 0] += w * __uint_as_float(dd.x << 16);
      facc[hh * 8 + 1] += w * __uint_as_float(dd.x & 0xffff0000u);
      facc[hh * 8 + 2] += w * __uint_as_float(dd.y << 16);
      facc[hh * 8 + 3] += w * __uint_as_float(dd.y & 0xffff0000u);
      facc[hh * 8 + 4] += w * __uint_as_float(dd.z << 16);
      facc[hh * 8 + 5] += w * __uint_as_float(dd.z & 0xffff0000u);
      facc[hh * 8 + 6] += w * __uint_as_float(dd.w << 16);
      facc[hh * 8 + 7] += w * __uint_as_float(dd.w & 0xffff0000u);
    }
  };

  float4 aA = z4, aB = z4;
  float mA = 0.f, mB = 0.f;
  uint4 dA[4] = {zu, zu, zu, zu};
  uint4 dB[4] = {zu, zu, zu, zu};

  LOADE(0, aA, mA, dA);
  for (int j = 0; j < deg; j += 16) {
    if (j + 8 < deg) LOADE(j + 8, aB, mB, dB); else mB = 0.f;
    PROC(aA, mA, dA);
    if (j + 16 < deg) LOADE(j + 16, aA, mA, dA); else mA = 0.f;
    PROC(aB, mB, dB);
  }

#pragma unroll
  for (int o = 8; o <= 32; o <<= 1) {
    ds.x += __shfl_xor(ds.x, o, 64);
    ds.y += __shfl_xor(ds.y, o, 64);
    ds.z += __shfl_xor(ds.z, o, 64);
    ds.w += __shfl_xor(ds.w, o, 64);
  }
  float iv0 = 1.f / (ds.x + 1e-16f);
  float iv1 = 1.f / (ds.y + 1e-16f);
  float iv2 = 1.f / (ds.z + 1e-16f);
  float iv3 = 1.f / (ds.w + 1e-16f);

  float v[8];
#pragma unroll
  for (int u = 0; u < 8; ++u)
    v[u] = facc[u] * iv0 + facc[8 + u] * iv1 + facc[16 + u] * iv2 + facc[24 + u] * iv3;

#pragma unroll
  for (int u = 0; u < 8; ++u) {
    v[u] += __shfl_xor(v[u], 8, 64);
    v[u] += __shfl_xor(v[u], 16, 64);
    v[u] += __shfl_xor(v[u], 32, 64);
  }

  if (slot < 2) {  // lane (slot, cp) writes channels cp*8 + slot*4 .. +3
    float o0 = (slot == 0) ? v[0] : v[4];
    float o1 = (slot == 0) ? v[1] : v[5];
    float o2 = (slot == 0) ? v[2] : v[6];
    float o3 = (slot == 0) ? v[3] : v[7];
    int chn = cp * 8 + slot * 4;
    float4 b4 = *reinterpret_cast<const float4*>(&bias[chn]);
    o0 = fmaxf(0.25f * o0 + b4.x, 0.f);
    o1 = fmaxf(0.25f * o1 + b4.y, 0.f);
    o2 = fmaxf(0.25f * o2 + b4.z, 0.f);
    o3 = fmaxf(0.25f * o3 + b4.w, 0.f);
    if (out_f32) {
      *reinterpret_cast<float4*>(&out_f32[(size_t)n * CHID + chn]) =
          make_float4(o0, o1, o2, o3);
    } else {
      float of[4] = {o0, o1, o2, o3};
      unsigned short b16[4];
#pragma unroll
      for (int u = 0; u < 4; ++u) {
        __hip_bfloat16 bh = __float2bfloat16(of[u]);
        b16[u] = *reinterpret_cast<unsigned short*>(&bh);
      }
      *reinterpret_cast<uint2*>(&out_bf[(size_t)n * CHID + chn]) =
          *reinterpret_cast<uint2*>(b16);
    }
  }
}

// ----------------- launch -----------------

extern "C" void kernel_launch(void* const* d_in, const int* in_sizes, int n_in,
                              void* d_out, int out_size, void* d_ws, size_t ws_size,
                              hipStream_t stream) {
  const float* x   = (const float*)d_in[0];
  const int*   ei  = (const int*)d_in[1];
  const float* W1  = (const float*)d_in[2];
  const float* as1 = (const float*)d_in[3];
  const float* ad1 = (const float*)d_in[4];
  const float* b1  = (const float*)d_in[5];
  const float* W2  = (const float*)d_in[6];
  const float* as2 = (const float*)d_in[7];
  const float* ad2 = (const float*)d_in[8];
  const float* b2  = (const float*)d_in[9];
  const float* W3  = (const float*)d_in[10];
  const float* as3 = (const float*)d_in[11];
  const float* ad3 = (const float*)d_in[12];
  const float* b3  = (const float*)d_in[13];

  int N  = in_sizes[0] / 128;
  int E  = in_sizes[1] / 2;
  int EP = E + N;
  int NB = (N + 255) / 256;  // scan chunks

  // workspace carve-up (all 16B-aligned)
  __hip_bfloat16* h    = (__hip_bfloat16*)d_ws;         // N*256
  __hip_bfloat16* x1b  = h + (size_t)N * HC;            // N*128
  __hip_bfloat16* xb   = x1b + (size_t)N * 128;         // N*64
  __hip_bfloat16* w1b  = xb + (size_t)N * CHID;         // 256*128
  __hip_bfloat16* w2b  = w1b + 256 * 128;               // 256*64
  __hip_bfloat16* w3b  = w2b + 256 * 64;                // 256*64
  float* asrc_n = (float*)(w3b + 256 * 64);             // N*4
  float* adst_n = asrc_n + (size_t)N * NH;              // N*4
  int*   deg    = (int*)(adst_n + (size_t)N * NH);      // N
  int*   cursor = deg + N;                              // N
  int*   row_off= cursor + N;                           // N+1
  int*   part   = row_off + (N + 1);                    // NB
  int*   ssrc   = part + ((NB + 3) & ~3);               // EP+8

  hipMemsetAsync(deg, 0, sizeof(int) * (size_t)2 * N, stream);  // deg + cursor
  int eb = (EP + 8 + 255) / 256;
  hist_kernel<<<eb, 256, 0, stream>>>(ei, E, N, deg);
  partial_sum_kernel<<<NB, 256, 0, stream>>>(deg, part, N);
  scan_part_kernel<<<1, 256, 0, stream>>>(part, NB, row_off, N);
  row_off_kernel<<<NB, 256, 0, stream>>>(deg, part, row_off, N);
  scatter_kernel<<<eb, 256, 0, stream>>>(ei, E, N, row_off, cursor, ssrc);

  int n4 = N * 128 / 4;
  prep_kernel<<<(n4 + 65536 + 255) / 256, 256, 0, stream>>>(x, x1b, n4,
                                                            W1, W2, W3, w1b, w2b, w3b);

  (void)hipFuncSetAttribute(reinterpret_cast<const void*>(&gemm_mfma_kernel<128>),
                            hipFuncAttributeMaxDynamicSharedMemorySize, 65536);
  (void)hipFuncSetAttribute(reinterpret_cast<const void*>(&gemm_mfma_kernel<64>),
                            hipFuncAttributeMaxDynamicSharedMemorySize, 65536);

  int RG = (N + 63) / 64;         // 64-row groups (782)
  dim3 ggrid(RG, 2);              // 1 group per block; LDS reused for epilogue
  int ablocks = (N + 3) / 4;      // one node per wave, 4 waves per block

  // layer 1 (K=128, LDS 32KB/block)
  gemm_mfma_kernel<128><<<ggrid, 256, 32768, stream>>>(x1b, w1b, as1, ad1,
                                                       h, asrc_n, adst_n, N, RG);
  aggregate_kernel<<<ablocks, 256, 0, stream>>>(row_off, ssrc, h, asrc_n, adst_n, b1,
                                                xb, nullptr, N);
  // layer 2 (K=64, LDS 16KB/block)
  gemm_mfma_kernel<64><<<ggrid, 256, 16384, stream>>>(xb, w2b, as2, ad2,
                                                      h, asrc_n, adst_n, N, RG);
  aggregate_kernel<<<ablocks, 256, 0, stream>>>(row_off, ssrc, h, asrc_n, adst_n, b2,
                                                xb, nullptr, N);
  // layer 3 (K=64)
  gemm_mfma_kernel<64><<<ggrid, 256, 16384, stream>>>(xb, w3b, as3, ad3,
                                                      h, asrc_n, adst_n, N, RG);
  aggregate_kernel<<<ablocks, 256, 0, stream>>>(row_off, ssrc, h, asrc_n, adst_n, b3,
                                                nullptr, (float*)d_out, N);
}